// Round 1
// baseline (1564.340 us; speedup 1.0000x reference)
//
#include <hip/hip_runtime.h>

// bf16 MFMA fragment types (gfx950: __builtin_amdgcn_mfma_f32_16x16x32_bf16 takes V8bf16)
typedef __bf16 bf16x8 __attribute__((ext_vector_type(8)));
typedef float  f32x4  __attribute__((ext_vector_type(4)));

__device__ __forceinline__ f32x4 mfma16(bf16x8 a, bf16x8 b, f32x4 c) {
    return __builtin_amdgcn_mfma_f32_16x16x32_bf16(a, b, c, 0, 0, 0);
}

// ---------------------------------------------------------------------------
// Kernel 0: weight prep. wqkv_t[c][k] = qkv_w[k][c] * (c<512 ? 1/sqrt(32) : 1)
//           wp_t[c][k]   = proj_w[k][c]
//           bias_eff[c]  = qkv_b[c] * (c<512 ? 1/sqrt(32) : 1)
// Transposed layout => MFMA B-fragment reads 8 contiguous k per lane.
// ---------------------------------------------------------------------------
__global__ void kprep(const float* __restrict__ qkvw, const float* __restrict__ qkvb,
                      const float* __restrict__ projw,
                      __bf16* __restrict__ wqkv_t, __bf16* __restrict__ wp_t,
                      float* __restrict__ bias_eff)
{
    const float s = 0.17677669529663687f; // 32^-0.5
    int idx = blockIdx.x * 256 + threadIdx.x;
    if (idx < 786432) {                       // qkv_w^T : [1536][512]
        int c = idx >> 9, k = idx & 511;
        float v = qkvw[k * 1536 + c];
        if (c < 512) v *= s;                  // fold q-scale into q columns
        wqkv_t[idx] = (__bf16)v;
    } else if (idx < 1048576) {               // proj_w^T : [512][512]
        int j = idx - 786432;
        int c = j >> 9, k = j & 511;
        wp_t[j] = (__bf16)projw[k * 512 + c];
    } else if (idx < 1050112) {               // bias (scaled for q part)
        int c = idx - 1048576;
        float v = qkvb[c];
        if (c < 512) v *= s;
        bias_eff[c] = v;
    }
}

// ---------------------------------------------------------------------------
// Kernel A: fused QKV projection + masked attention, one block per window b.
// LDS: x (bf16, A-frag-swizzled, 64KB) + 4 waves * 12KB (q,k: 8KB (p aliases),
// vt: 4KB). Each wave owns 4 heads. Attention output written bf16, swizzled
// in proj-A-fragment order, into d_out + b*122880 (d_out used as scratch;
// kernel B overwrites with final fp32).
//
// Fragment layouts (verified, cdna_hip_programming.md §3):
//   A: lane holds A[m=lane&15][k=(lane>>4)*8+j]
//   B: lane holds B[k=(lane>>4)*8+j][n=lane&15]
//   C/D: lane holds D[row=(lane>>4)*4+reg][col=lane&15]
// ---------------------------------------------------------------------------
__global__ __launch_bounds__(256, 1) void ka_fused(
    const float*  __restrict__ xin,       // [2048][60][512] fp32
    const __bf16* __restrict__ wqkv,      // [1536][512] transposed, q-scaled
    const float*  __restrict__ bias_eff,  // [1536]
    char*         __restrict__ aobase)    // = d_out
{
    const int b    = blockIdx.x;
    const int tid  = threadIdx.x;
    const int lane = tid & 63;
    const int w    = tid >> 6;
    const int q4   = lane >> 4;
    const int l15  = lane & 15;

    extern __shared__ char smem[];
    char* xs = smem;                        // [0, 65536): x swizzled
    char* wb = smem + 65536 + w * 12288;    // per-wave: q[0,4K) k[4K,8K) vt[8K,12K); p aliases [0,8K)

    const f32x4 fzero = {0.f, 0.f, 0.f, 0.f};

    // ---- stage x: fp32 -> bf16, zero-pad rows 60..63, A-frag swizzle ----
    // swizzled addr for (row r, k chunk k0): group=(k0>>5)*4+(r>>4),
    // lane slot=((k0>>3)&3)*16+(r&15)  -> conflict-free ds_read_b128 later.
#pragma unroll
    for (int j = 0; j < 16; ++j) {
        int ci = j * 256 + tid;             // 0..4095
        int r  = ci >> 6;
        int k0 = (ci & 63) << 3;
        float4 f0 = make_float4(0.f, 0.f, 0.f, 0.f), f1 = f0;
        if (r < 60) {
            const float4* s4 = reinterpret_cast<const float4*>(
                xin + ((size_t)b * 60 + r) * 512 + k0);
            f0 = s4[0]; f1 = s4[1];
        }
        bf16x8 v;
        v[0]=(__bf16)f0.x; v[1]=(__bf16)f0.y; v[2]=(__bf16)f0.z; v[3]=(__bf16)f0.w;
        v[4]=(__bf16)f1.x; v[5]=(__bf16)f1.y; v[6]=(__bf16)f1.z; v[7]=(__bf16)f1.w;
        int addr = ((((k0 >> 5) << 2) + (r >> 4)) * 64
                    + ((k0 >> 3) & 3) * 16 + (r & 15)) * 16;
        *reinterpret_cast<bf16x8*>(xs + addr) = v;
    }
    __syncthreads();

    for (int i = 0; i < 4; ++i) {
        const int h = (w << 2) + i;
        __threadfence_block();   // prior round's p/vt LDS reads before this round's writes

        // ---- Q/K/V projections for head h: [64x512] @ [512x32] ----
        for (int s = 0; s < 3; ++s) {
            const __bf16* wcol = wqkv + ((size_t)(s * 512 + h * 32 + l15) * 512) + q4 * 8;
            f32x4 acc[4][2];
#pragma unroll
            for (int mt = 0; mt < 4; ++mt)
#pragma unroll
                for (int n = 0; n < 2; ++n) acc[mt][n] = fzero;

#pragma unroll
            for (int kk = 0; kk < 16; ++kk) {
                bf16x8 a[4];
#pragma unroll
                for (int mt = 0; mt < 4; ++mt)
                    a[mt] = *reinterpret_cast<const bf16x8*>(
                        xs + (((kk << 2) + mt) * 64 + lane) * 16);
                bf16x8 bw[2];
#pragma unroll
                for (int n = 0; n < 2; ++n)
                    bw[n] = *reinterpret_cast<const bf16x8*>(
                        wcol + (size_t)(n * 16) * 512 + kk * 32);
#pragma unroll
                for (int mt = 0; mt < 4; ++mt)
#pragma unroll
                    for (int n = 0; n < 2; ++n)
                        acc[mt][n] = mfma16(a[mt], bw[n], acc[mt][n]);
            }
            float bs0 = bias_eff[s * 512 + h * 32 + l15];
            float bs1 = bias_eff[s * 512 + h * 32 + 16 + l15];
            // epilogue: C-layout -> swizzled per-wave LDS bufs
#pragma unroll
            for (int mt = 0; mt < 4; ++mt)
#pragma unroll
                for (int n = 0; n < 2; ++n)
#pragma unroll
                    for (int reg = 0; reg < 4; ++reg) {
                        float val = acc[mt][n][reg] + (n ? bs1 : bs0);
                        if (s < 2) {
                            // q/k: A/B-frag layout over [row][hd]
                            int hd = n * 16 + l15;
                            int addr = s * 4096
                                + ((mt * 64 + (hd >> 3) * 16 + q4 * 4 + reg) * 16)
                                + (hd & 7) * 2;
                            *reinterpret_cast<__bf16*>(wb + addr) = (__bf16)val;
                        } else {
                            // v: B-frag layout for PV (vt[hd][key])
                            int key = mt * 16 + q4 * 4 + reg;
                            int g   = ((mt >> 1) << 1) + n;   // (key>>5)*2 + (hd>>4)
                            int addr = 8192
                                + ((g * 64 + ((key >> 3) & 3) * 16 + l15) * 16)
                                + (key & 7) * 2;
                            *reinterpret_cast<__bf16*>(wb + addr) = (__bf16)val;
                        }
                    }
        }
        __threadfence_block();

        // ---- scores = Q K^T  (M=64,N=64,K=32 -> one MFMA K-step) ----
        bf16x8 qa[4], kb[4];
#pragma unroll
        for (int mt = 0; mt < 4; ++mt)
            qa[mt] = *reinterpret_cast<const bf16x8*>(wb + (mt * 64 + lane) * 16);
#pragma unroll
        for (int nt = 0; nt < 4; ++nt)
            kb[nt] = *reinterpret_cast<const bf16x8*>(wb + 4096 + (nt * 64 + lane) * 16);
        f32x4 sc[4][4];
#pragma unroll
        for (int mt = 0; mt < 4; ++mt)
#pragma unroll
            for (int nt = 0; nt < 4; ++nt)
                sc[mt][nt] = mfma16(qa[mt], kb[nt], fzero);

        // ---- masked softmax: row = mt*16+q4*4+reg lives in this lane's
        //      16-lane group (same q4); columns = 4 nt-tiles x l15 ----
        float inv_rs[4][4];
#pragma unroll
        for (int mt = 0; mt < 4; ++mt)
#pragma unroll
            for (int reg = 0; reg < 4; ++reg) {
                float m0 = fmaxf(fmaxf(sc[mt][0][reg], sc[mt][1][reg]), sc[mt][2][reg]);
                float v3 = (l15 < 12) ? sc[mt][3][reg] : -3.0e38f;  // keys 60..63 masked
                m0 = fmaxf(m0, v3);
#pragma unroll
                for (int d = 1; d < 16; d <<= 1)
                    m0 = fmaxf(m0, __shfl_xor(m0, d));
                float ssum = 0.f;
#pragma unroll
                for (int nt = 0; nt < 4; ++nt) {
                    float p = (nt == 3 && l15 >= 12) ? 0.f
                              : __expf(sc[mt][nt][reg] - m0);
                    sc[mt][nt][reg] = p;
                    ssum += p;
                }
#pragma unroll
                for (int d = 1; d < 16; d <<= 1)
                    ssum += __shfl_xor(ssum, d);
                inv_rs[mt][reg] = 1.f / ssum;   // normalize after PV (same row mapping)
            }

        // ---- P (C-layout) -> LDS in A-frag layout (aliases q/k bufs) ----
#pragma unroll
        for (int mt = 0; mt < 4; ++mt)
#pragma unroll
            for (int nt = 0; nt < 4; ++nt)
#pragma unroll
                for (int reg = 0; reg < 4; ++reg) {
                    int addr = (((((nt >> 1) << 2) + mt) * 64)
                                + ((((nt & 1) << 1) + (l15 >> 3)) * 16 + q4 * 4 + reg)) * 16
                               + (l15 & 7) * 2;
                    *reinterpret_cast<__bf16*>(wb + addr) = (__bf16)sc[mt][nt][reg];
                }
        __threadfence_block();

        // ---- O = P V  (M=64,N=32,K=64 -> 2 K-steps) ----
        bf16x8 pa[4][2], vb[2][2];
#pragma unroll
        for (int mt = 0; mt < 4; ++mt)
#pragma unroll
            for (int ks = 0; ks < 2; ++ks)
                pa[mt][ks] = *reinterpret_cast<const bf16x8*>(
                    wb + (((ks << 2) + mt) * 64 + lane) * 16);
#pragma unroll
        for (int ks = 0; ks < 2; ++ks)
#pragma unroll
            for (int n = 0; n < 2; ++n)
                vb[ks][n] = *reinterpret_cast<const bf16x8*>(
                    wb + 8192 + (((ks << 1) + n) * 64 + lane) * 16);
        f32x4 o[4][2];
#pragma unroll
        for (int mt = 0; mt < 4; ++mt)
#pragma unroll
            for (int n = 0; n < 2; ++n) {
                o[mt][n] = mfma16(pa[mt][0], vb[0][n], fzero);
                o[mt][n] = mfma16(pa[mt][1], vb[1][n], o[mt][n]);
            }

        // ---- store attention out: bf16, proj-A-frag swizzled, into d_out region b ----
        // head h covers proj K-step kk=h exactly (32 cols).
        char* aob = aobase + (size_t)b * 122880;
#pragma unroll
        for (int mt = 0; mt < 4; ++mt)
#pragma unroll
            for (int n = 0; n < 2; ++n)
#pragma unroll
                for (int reg = 0; reg < 4; ++reg) {
                    float val = o[mt][n][reg] * inv_rs[mt][reg];
                    int addr = ((((h << 2) + mt) * 64)
                                + ((n * 2 + (l15 >> 3)) * 16 + q4 * 4 + reg)) * 16
                               + (l15 & 7) * 2;
                    *reinterpret_cast<__bf16*>(aob + addr) = (__bf16)val;
                }
    }
}

// ---------------------------------------------------------------------------
// Kernel B: output projection. Stage the 64KB swizzled bf16 attention output
// (living in this block's own d_out region) to LDS, then [64x512]@[512x512]
// MFMA, write fp32 rows 0..59 over the same region. Reads are entirely
// before writes within the block; regions are disjoint across blocks.
// ---------------------------------------------------------------------------
__global__ __launch_bounds__(256, 2) void kb_proj(
    const __bf16* __restrict__ wp,     // [512][512] transposed
    const float*  __restrict__ projb,  // [512]
    char*         __restrict__ dout)
{
    const int b    = blockIdx.x;
    const int tid  = threadIdx.x;
    const int lane = tid & 63;
    const int w    = tid >> 6;
    const int q4   = lane >> 4;
    const int l15  = lane & 15;
    extern __shared__ char smem[];                 // 65536
    char* aob = dout + (size_t)b * 122880;
    const f32x4 fzero = {0.f, 0.f, 0.f, 0.f};

#pragma unroll
    for (int j = 0; j < 16; ++j) {
        int ci = j * 256 + tid;                    // 4096 x 16B chunks
        reinterpret_cast<uint4*>(smem)[ci] = reinterpret_cast<const uint4*>(aob)[ci];
    }
    __syncthreads();

    float* outp = reinterpret_cast<float*>(aob);
    for (int pass = 0; pass < 4; ++pass) {
        const int nt0 = pass * 8 + w * 2;          // n-tiles: 32 total over 4 waves x 4 passes x 2
        f32x4 acc[4][2];
#pragma unroll
        for (int mt = 0; mt < 4; ++mt)
#pragma unroll
            for (int n = 0; n < 2; ++n) acc[mt][n] = fzero;

#pragma unroll
        for (int kk = 0; kk < 16; ++kk) {
            bf16x8 a[4];
#pragma unroll
            for (int mt = 0; mt < 4; ++mt)
                a[mt] = *reinterpret_cast<const bf16x8*>(
                    smem + (((kk << 2) + mt) * 64 + lane) * 16);
            bf16x8 bw[2];
#pragma unroll
            for (int n = 0; n < 2; ++n)
                bw[n] = *reinterpret_cast<const bf16x8*>(
                    wp + (size_t)((nt0 + n) * 16 + l15) * 512 + kk * 32 + q4 * 8);
#pragma unroll
            for (int mt = 0; mt < 4; ++mt)
#pragma unroll
                for (int n = 0; n < 2; ++n)
                    acc[mt][n] = mfma16(a[mt], bw[n], acc[mt][n]);
        }
#pragma unroll
        for (int n = 0; n < 2; ++n) {
            int c = (nt0 + n) * 16 + l15;
            float bias = projb[c];
#pragma unroll
            for (int mt = 0; mt < 4; ++mt)
#pragma unroll
                for (int reg = 0; reg < 4; ++reg) {
                    int row = mt * 16 + q4 * 4 + reg;
                    if (row < 60)
                        outp[row * 512 + c] = acc[mt][n][reg] + bias;
                }
        }
    }
}

// ---------------------------------------------------------------------------
extern "C" void kernel_launch(void* const* d_in, const int* in_sizes, int n_in,
                              void* d_out, int out_size, void* d_ws, size_t ws_size,
                              hipStream_t stream)
{
    const float* xin   = (const float*)d_in[0];  // [2048,60,512]
    const float* qkvw  = (const float*)d_in[1];  // [512,1536]
    const float* qkvb  = (const float*)d_in[2];  // [1536]
    const float* projw = (const float*)d_in[3];  // [512,512]
    const float* projb = (const float*)d_in[4];  // [512]

    __bf16* wqkv_t   = (__bf16*)d_ws;                          // 786432 elems
    __bf16* wp_t     = wqkv_t + 786432;                        // 262144 elems
    float*  bias_eff = (float*)((char*)d_ws + 2097152);        // 1536 fp32
    // total ws use: ~2.1 MB

    (void)hipFuncSetAttribute(reinterpret_cast<const void*>(ka_fused),
                              hipFuncAttributeMaxDynamicSharedMemorySize, 114688);
    (void)hipFuncSetAttribute(reinterpret_cast<const void*>(kb_proj),
                              hipFuncAttributeMaxDynamicSharedMemorySize, 65536);

    kprep<<<dim3(4102), dim3(256), 0, stream>>>(qkvw, qkvb, projw,
                                                wqkv_t, wp_t, bias_eff);
    ka_fused<<<dim3(2048), dim3(256), 114688, stream>>>(xin, wqkv_t, bias_eff,
                                                        (char*)d_out);
    kb_proj<<<dim3(2048), dim3(256), 65536, stream>>>(wp_t, projb, (char*)d_out);
}